// Round 4
// baseline (23241.655 us; speedup 1.0000x reference)
//
#include <hip/hip_runtime.h>
#include <hip/hip_bf16.h>

// LSTM: B=128, T=1024, D=H=768.
// R4: kill the poll storm. t-indexed arrival counters (cnt[t][band][8 subs],
// one 64B line per sub), single atomicAdd per wave per step, 8-line polls
// with s_sleep backoff. 4-way split accumulators to break the serial MFMA
// dependence chain; vmcnt(24)/vmcnt(0) split on the h-load drain.

typedef __attribute__((ext_vector_type(8))) short short8v;   // 8 bf16 = 4 VGPR
typedef __attribute__((ext_vector_type(16))) float f32x16;   // 32x32 acc

constexpr int B_ = 128, T_ = 1024, D_ = 768, H_ = 768;
constexpr int NWG = 96;          // j-groups (8 h-cols each)

// counters: [1025 steps][4 bands][8 subs], each padded to 64B (16 u32)
constexpr size_t CNT_OFF  = 0;
constexpr size_t CNT_U32  = 1025ull * 4 * 8 * 16;      // 524800 u32 = 2099200 B
constexpr size_t HB_OFF   = 2101248;                   // 2*96*128*8 bf16 = 393216 B
constexpr size_t BIAS_OFF = HB_OFF + 393216;           // 3072 f32 = 12288 B
constexpr size_t WC_OFF   = BIAS_OFF + 12288;          // 9437184 B
constexpr size_t XT_OFF   = WC_OFF + 9437184;          // 201326592 B
constexpr size_t WS_NEED  = XT_OFF + 201326592;        // ~213.3 MB

__device__ __forceinline__ unsigned short f2bf(float f) {
  union { float f; unsigned u; } v; v.f = f;
  unsigned r = v.u + 0x7FFF + ((v.u >> 16) & 1);       // RNE
  return (unsigned short)(r >> 16);
}
__device__ __forceinline__ float sigmf(float x) { return 1.0f / (1.0f + __expf(-x)); }
__device__ __forceinline__ float tanhf_(float x) {
  float ax = fabsf(x);
  float e = __expf(-2.0f * ax);
  float t = (1.0f - e) / (1.0f + e);
  return copysignf(t, x);
}

// ---------------- P1: x -> xTb[t][kb][b][ko] bf16, LDS-tiled transpose ----
__global__ void k_xT(const float* __restrict__ x, unsigned short* __restrict__ xTb) {
  __shared__ float tile[16][776];
  const int t = blockIdx.x;
  const int tid = threadIdx.x;
  for (int chunk = 0; chunk < 8; ++chunk) {
    #pragma unroll
    for (int i = 0; i < 12; ++i) {
      int id = i * 256 + tid;
      int bl = id / 192, d4 = id % 192;
      int b = chunk * 16 + bl;
      float4 v = *(const float4*)(x + ((size_t)b * T_ + t) * D_ + d4 * 4);
      *(float4*)&tile[bl][d4 * 4] = v;
    }
    __syncthreads();
    #pragma unroll
    for (int i = 0; i < 6; ++i) {
      int id = i * 256 + tid;
      int kb = id >> 4, bl = id & 15;
      int b = chunk * 16 + bl;
      const float* src = &tile[bl][kb * 8];
      unsigned short tmp[8];
      #pragma unroll
      for (int k = 0; k < 8; ++k) tmp[k] = f2bf(src[k]);
      *(short8v*)(xTb + (((size_t)t * 96 + kb) * 128 + b) * 8) = *(short8v*)tmp;
    }
    __syncthreads();
  }
}

// ---------------- P2: weight slices, swizzled ----------------------------
__global__ void k_prep_w(const float* __restrict__ wih, const float* __restrict__ whh,
                         unsigned short* __restrict__ Wc) {
  int id  = blockIdx.x * 256 + threadIdx.x;            // exactly 589824
  int wj  = id / 6144;
  int rem = id - wj * 6144;
  int src = rem / 3072; rem -= src * 3072;
  int r   = rem / 96;
  int kcp = rem - r * 96;
  int kc  = kcp ^ (r & 15);
  int grow = (r >> 3) * H_ + wj * 8 + (r & 7);
  const float* W = (src == 0) ? whh : wih;
  const float* p = W + (size_t)grow * D_ + kc * 8;
  float4 v0 = *(const float4*)p;
  float4 v1 = *(const float4*)(p + 4);
  ushort4 o0 = {f2bf(v0.x), f2bf(v0.y), f2bf(v0.z), f2bf(v0.w)};
  ushort4 o1 = {f2bf(v1.x), f2bf(v1.y), f2bf(v1.z), f2bf(v1.w)};
  *(ushort4*)(Wc + (size_t)id * 8)     = o0;
  *(ushort4*)(Wc + (size_t)id * 8 + 4) = o1;
}

// ---------------- P3: bias, h0 -> blocked bf16 buf0, zero counters -------
__global__ void k_prep_s(const float* __restrict__ h0,
                         const float* __restrict__ bih, const float* __restrict__ bhh,
                         unsigned short* __restrict__ hb, float* __restrict__ bias_c,
                         unsigned* __restrict__ cnt) {
  int id = blockIdx.x * 256 + threadIdx.x;             // exactly 98304
  int b = id / 768, j = id - b * 768;
  hb[(size_t)(j >> 3) * 1024 + b * 8 + (j & 7)] = f2bf(h0[id]);
  if (id < 3072) {
    int wj = id >> 5, r = id & 31;
    int grow = (r >> 3) * H_ + wj * 8 + (r & 7);
    bias_c[id] = bih[grow] + bhh[grow];
  }
  for (size_t i = id; i < CNT_U32; i += 98304) cnt[i] = 0;
}

// ---------------- main recurrent kernel ----------------------------------
__launch_bounds__(256, 1)
__global__ void k_lstm(const unsigned short* __restrict__ xTb,
                       const unsigned short* __restrict__ Wc,
                       const float* __restrict__ bias_c,
                       const float* __restrict__ c0,
                       unsigned short* __restrict__ hb,   // [2][96][128][8] bf16
                       unsigned* cnt,                     // [1025][4][8][16]
                       float* __restrict__ out,
                       float* __restrict__ hT,
                       float* __restrict__ cT) {
  __shared__ __align__(16) unsigned short Wl[2 * 32 * 768];   // 96 KB
  __shared__ float bias_l[32];

  const int wj   = blockIdx.x;
  const int tid  = threadIdx.x;
  const int wave = tid >> 6;          // band: batch rows wave*32..+32
  const int lane = tid & 63;
  const int col  = lane & 31;
  const int kh   = lane >> 5;
  const int sw   = col & 15;

  {
    const short8v* s = (const short8v*)(Wc + (size_t)wj * 49152);
    short8v* d = (short8v*)Wl;
    for (int i = tid; i < 6144; i += 256) d[i] = s[i];
    if (tid < 32) bias_l[tid] = bias_c[wj * 32 + tid];
  }
  __syncthreads();

  const int bg = wave * 32 + col;     // global batch row
  const int jg = wj * 8 + 4 * kh;

  float c_r[4];
  {
    float4 v = *(const float4*)(c0 + (size_t)bg * H_ + jg);
    c_r[0] = v.x; c_r[1] = v.y; c_r[2] = v.z; c_r[3] = v.w;
  }

  const char* wlb = (const char*)Wl;
  const int wrow0 = col * 1536;             // W_hh A-row base (bytes)
  const int wrow1 = 49152 + col * 1536;     // W_ih A-row base

  // counters: my band's 8 sub-counters (one per 64B line), my arrive slot
  unsigned* cnt_poll0 = cnt + ((size_t)wave * 8 + (lane & 7)) * 16;   // + t*512
  unsigned* cnt_arr0  = cnt + ((size_t)wave * 8 + (wj & 7)) * 16;     // + (t+1)*512

  float bias_r[16];
  #pragma unroll
  for (int q = 0; q < 16; ++q) bias_r[q] = bias_l[(q & 3) + 8 * (q >> 2) + 4 * kh];

  f32x16 accs[4];
  { // phase X for t=0
    #pragma unroll
    for (int q = 0; q < 16; ++q) {
      accs[0][q] = bias_r[q]; accs[1][q] = 0.f; accs[2][q] = 0.f; accs[3][q] = 0.f;
    }
    const unsigned short* xp = xTb + (size_t)kh * 1024 + bg * 8;
    #pragma unroll
    for (int f = 0; f < 48; ++f) {
      short8v w = *(const short8v*)(wlb + wrow1 + (((2 * f + kh) ^ sw) << 4));
      short8v xv = *(const short8v*)(xp + f * 2048);
      accs[f & 3] = __builtin_amdgcn_mfma_f32_32x32x16_bf16(w, xv, accs[f & 3], 0, 0, 0);
    }
  }

  for (int t = 0; t < T_; ++t) {
    if (t > 0) {
      const unsigned* cw = cnt_poll0 + (size_t)t * 512;   // 4*8*16 u32 per step
      for (;;) {
        unsigned v = __hip_atomic_load(cw, __ATOMIC_RELAXED, __HIP_MEMORY_SCOPE_AGENT);
        if (__all(v >= 12u)) break;
        __builtin_amdgcn_s_sleep(4);
      }
      asm volatile("" ::: "memory");
    }

    // phase H: 48 coalesced uncached 16B loads, split-drain MFMA
    short8v hfrag[48];
    {
      const unsigned short* hp =
          hb + (size_t)(t & 1) * 98304 + (size_t)kh * 1024 + bg * 8;
      #pragma unroll
      for (int f = 0; f < 48; ++f) {
        asm volatile("global_load_dwordx4 %0, %1, off sc0 sc1"
                     : "=v"(hfrag[f]) : "v"(hp + f * 2048));
      }
    }
    asm volatile("s_waitcnt vmcnt(24)" ::: "memory");
    __builtin_amdgcn_sched_barrier(0);
    #pragma unroll
    for (int f = 0; f < 24; ++f) {
      short8v w = *(const short8v*)(wlb + wrow0 + (((2 * f + kh) ^ sw) << 4));
      accs[f & 3] = __builtin_amdgcn_mfma_f32_32x32x16_bf16(w, hfrag[f], accs[f & 3], 0, 0, 0);
    }
    asm volatile("s_waitcnt vmcnt(0)" ::: "memory");
    __builtin_amdgcn_sched_barrier(0);
    #pragma unroll
    for (int f = 24; f < 48; ++f) {
      short8v w = *(const short8v*)(wlb + wrow0 + (((2 * f + kh) ^ sw) << 4));
      accs[f & 3] = __builtin_amdgcn_mfma_f32_32x32x16_bf16(w, hfrag[f], accs[f & 3], 0, 0, 0);
    }

    // reduce 4 partial accumulators, then gate
    f32x16 g;
    #pragma unroll
    for (int q = 0; q < 16; ++q)
      g[q] = (accs[0][q] + accs[1][q]) + (accs[2][q] + accs[3][q]);

    float hnew[4];
    #pragma unroll
    for (int m = 0; m < 4; ++m) {
      float gi = g[m];
      float gf = g[4 + m];
      float gg = g[8 + m];
      float go = g[12 + m];
      float cn = sigmf(gf) * c_r[m] + sigmf(gi) * tanhf_(gg);
      c_r[m] = cn;
      hnew[m] = sigmf(go) * tanhf_(cn);
    }

    // h exchange: coalesced 8B write-through store (agent scope)
    union { ushort4 s; unsigned long long u; } hv;
    hv.s = (ushort4){f2bf(hnew[0]), f2bf(hnew[1]), f2bf(hnew[2]), f2bf(hnew[3])};
    __hip_atomic_store(
        (unsigned long long*)(hb + (size_t)((t + 1) & 1) * 98304 +
                              (size_t)wj * 1024 + bg * 8 + 4 * kh),
        hv.u, __ATOMIC_RELAXED, __HIP_MEMORY_SCOPE_AGENT);

    // release: wait h-store ack at coherence point, then one arrival add
    asm volatile("s_waitcnt vmcnt(0)" ::: "memory");
    if (lane == 0)
      __hip_atomic_fetch_add(cnt_arr0 + (size_t)(t + 1) * 512, 1u,
                             __ATOMIC_RELAXED, __HIP_MEMORY_SCOPE_AGENT);

    // out stores AFTER the release (off the critical path)
    float4 ov = make_float4(hnew[0], hnew[1], hnew[2], hnew[3]);
    *(float4*)(out + ((size_t)bg * T_ + t) * H_ + jg) = ov;
    if (t == T_ - 1) {
      *(float4*)(hT + (size_t)bg * H_ + jg) = ov;
      float4 cv = make_float4(c_r[0], c_r[1], c_r[2], c_r[3]);
      *(float4*)(cT + (size_t)bg * H_ + jg) = cv;
    }

    // phase X for t+1 (cached coalesced loads), in the shadow of the wait
    if (t + 1 < T_) {
      #pragma unroll
      for (int q = 0; q < 16; ++q) {
        accs[0][q] = bias_r[q]; accs[1][q] = 0.f; accs[2][q] = 0.f; accs[3][q] = 0.f;
      }
      const unsigned short* xp =
          xTb + (size_t)(t + 1) * 98304 + (size_t)kh * 1024 + bg * 8;
      #pragma unroll
      for (int f = 0; f < 48; ++f) {
        short8v w = *(const short8v*)(wlb + wrow1 + (((2 * f + kh) ^ sw) << 4));
        short8v xv = *(const short8v*)(xp + f * 2048);
        accs[f & 3] = __builtin_amdgcn_mfma_f32_32x32x16_bf16(w, xv, accs[f & 3], 0, 0, 0);
      }
    }
  }
}

extern "C" void kernel_launch(void* const* d_in, const int* in_sizes, int n_in,
                              void* d_out, int out_size, void* d_ws, size_t ws_size,
                              hipStream_t stream) {
  const float* x   = (const float*)d_in[0];
  const float* h0  = (const float*)d_in[1];
  const float* c0  = (const float*)d_in[2];
  const float* wih = (const float*)d_in[3];
  const float* whh = (const float*)d_in[4];
  const float* bih = (const float*)d_in[5];
  const float* bhh = (const float*)d_in[6];

  float* out = (float*)d_out;
  float* hT  = out + (size_t)B_ * T_ * H_;
  float* cT  = hT + (size_t)B_ * H_;

  if (ws_size < WS_NEED) return;  // visible failure instead of OOB corruption

  char* ws = (char*)d_ws;
  unsigned*       cnt   = (unsigned*)(ws + CNT_OFF);
  unsigned short* hb    = (unsigned short*)(ws + HB_OFF);
  float*          biasc = (float*)(ws + BIAS_OFF);
  unsigned short* Wc    = (unsigned short*)(ws + WC_OFF);
  unsigned short* xTp   = (unsigned short*)(ws + XT_OFF);

  k_xT<<<dim3(T_), dim3(256), 0, stream>>>(x, xTp);
  k_prep_w<<<dim3(589824 / 256), dim3(256), 0, stream>>>(wih, whh, Wc);
  k_prep_s<<<dim3((B_ * H_) / 256), dim3(256), 0, stream>>>(h0, bih, bhh, hb, biasc, cnt);
  k_lstm<<<dim3(NWG), dim3(256), 0, stream>>>(xTp, Wc, biasc, c0, hb, cnt, out, hT, cT);
}

// Round 5
// 23132.674 us; speedup vs baseline: 1.0047x; 1.0047x over previous
//
#include <hip/hip_runtime.h>
#include <hip/hip_bf16.h>

// LSTM: B=128, T=1024, D=H=768.
// R5: t-indexed h history (hb[1025][96][128][8] bf16) => consumer h-reads are
// plain CACHED loads (L2 dedups the 12 WGs per XCD; 12x less fabric traffic).
// Write-once-per-line removes staleness: any L2 copy was fetched post-poll.
// Producers unchanged: sc1 write-through + vmcnt(0) + arrival counters.
// Adaptive: if ws_size < ~414MB, fall back to 2-slot uncached (R4 behavior).

typedef __attribute__((ext_vector_type(8))) short short8v;   // 8 bf16 = 4 VGPR
typedef __attribute__((ext_vector_type(16))) float f32x16;   // 32x32 acc

constexpr int B_ = 128, T_ = 1024, D_ = 768, H_ = 768;
constexpr int NWG = 96;          // j-groups (8 h-cols each)

// counters: [1025 steps][4 bands][8 subs], each padded to 64B (16 u32)
constexpr size_t CNT_U32   = 1025ull * 4 * 8 * 16;     // 524800 u32
constexpr size_t CNT_BYTES = 2101248;                  // rounded up, 16B-aligned
constexpr size_t HSLOT_SH  = 96ull * 128 * 8;          // 98304 shorts = 196608 B
constexpr size_t HB_FULL   = 1025ull * HSLOT_SH * 2;   // 201572352 B
constexpr size_t HB_MIN    = 2ull * HSLOT_SH * 2;      // 393216 B
constexpr size_t BIAS_B    = 12288;
constexpr size_t WC_B      = 9437184;
constexpr size_t XT_B      = 201326592;

__device__ __forceinline__ unsigned short f2bf(float f) {
  union { float f; unsigned u; } v; v.f = f;
  unsigned r = v.u + 0x7FFF + ((v.u >> 16) & 1);       // RNE
  return (unsigned short)(r >> 16);
}
__device__ __forceinline__ float sigmf(float x) { return 1.0f / (1.0f + __expf(-x)); }
__device__ __forceinline__ float tanhf_(float x) {
  float ax = fabsf(x);
  float e = __expf(-2.0f * ax);
  float t = (1.0f - e) / (1.0f + e);
  return copysignf(t, x);
}

// ---------------- P1: x -> xTb[t][kb][b][ko] bf16, LDS-tiled transpose ----
__global__ void k_xT(const float* __restrict__ x, unsigned short* __restrict__ xTb) {
  __shared__ float tile[16][776];
  const int t = blockIdx.x;
  const int tid = threadIdx.x;
  for (int chunk = 0; chunk < 8; ++chunk) {
    #pragma unroll
    for (int i = 0; i < 12; ++i) {
      int id = i * 256 + tid;
      int bl = id / 192, d4 = id % 192;
      int b = chunk * 16 + bl;
      float4 v = *(const float4*)(x + ((size_t)b * T_ + t) * D_ + d4 * 4);
      *(float4*)&tile[bl][d4 * 4] = v;
    }
    __syncthreads();
    #pragma unroll
    for (int i = 0; i < 6; ++i) {
      int id = i * 256 + tid;
      int kb = id >> 4, bl = id & 15;
      int b = chunk * 16 + bl;
      const float* src = &tile[bl][kb * 8];
      unsigned short tmp[8];
      #pragma unroll
      for (int k = 0; k < 8; ++k) tmp[k] = f2bf(src[k]);
      *(short8v*)(xTb + (((size_t)t * 96 + kb) * 128 + b) * 8) = *(short8v*)tmp;
    }
    __syncthreads();
  }
}

// ---------------- P2: weight slices, swizzled ----------------------------
__global__ void k_prep_w(const float* __restrict__ wih, const float* __restrict__ whh,
                         unsigned short* __restrict__ Wc) {
  int id  = blockIdx.x * 256 + threadIdx.x;            // exactly 589824
  int wj  = id / 6144;
  int rem = id - wj * 6144;
  int src = rem / 3072; rem -= src * 3072;
  int r   = rem / 96;
  int kcp = rem - r * 96;
  int kc  = kcp ^ (r & 15);
  int grow = (r >> 3) * H_ + wj * 8 + (r & 7);
  const float* W = (src == 0) ? whh : wih;
  const float* p = W + (size_t)grow * D_ + kc * 8;
  float4 v0 = *(const float4*)p;
  float4 v1 = *(const float4*)(p + 4);
  ushort4 o0 = {f2bf(v0.x), f2bf(v0.y), f2bf(v0.z), f2bf(v0.w)};
  ushort4 o1 = {f2bf(v1.x), f2bf(v1.y), f2bf(v1.z), f2bf(v1.w)};
  *(ushort4*)(Wc + (size_t)id * 8)     = o0;
  *(ushort4*)(Wc + (size_t)id * 8 + 4) = o1;
}

// ---------------- P3: bias, h0 -> blocked bf16 slot0, zero counters ------
__global__ void k_prep_s(const float* __restrict__ h0,
                         const float* __restrict__ bih, const float* __restrict__ bhh,
                         unsigned short* __restrict__ hb, float* __restrict__ bias_c,
                         unsigned* __restrict__ cnt) {
  int id = blockIdx.x * 256 + threadIdx.x;             // exactly 98304
  int b = id / 768, j = id - b * 768;
  hb[(size_t)(j >> 3) * 1024 + b * 8 + (j & 7)] = f2bf(h0[id]);
  if (id < 3072) {
    int wj = id >> 5, r = id & 31;
    int grow = (r >> 3) * H_ + wj * 8 + (r & 7);
    bias_c[id] = bih[grow] + bhh[grow];
  }
  for (size_t i = id; i < CNT_U32; i += 98304) cnt[i] = 0;
}

// ---------------- main recurrent kernel ----------------------------------
template <bool CACHED>
__launch_bounds__(256, 1)
__global__ void k_lstm(const unsigned short* __restrict__ xTb,
                       const unsigned short* __restrict__ Wc,
                       const float* __restrict__ bias_c,
                       const float* __restrict__ c0,
                       unsigned short* __restrict__ hb,   // [S][96][128][8] bf16
                       unsigned* cnt,                     // [1025][4][8][16]
                       float* __restrict__ out,
                       float* __restrict__ hT,
                       float* __restrict__ cT) {
  __shared__ __align__(16) unsigned short Wl[2 * 32 * 768];   // 96 KB
  __shared__ float bias_l[32];

  const int wj   = blockIdx.x;
  const int tid  = threadIdx.x;
  const int wave = tid >> 6;          // band: batch rows wave*32..+32
  const int lane = tid & 63;
  const int col  = lane & 31;
  const int kh   = lane >> 5;
  const int sw   = col & 15;

  {
    const short8v* s = (const short8v*)(Wc + (size_t)wj * 49152);
    short8v* d = (short8v*)Wl;
    for (int i = tid; i < 6144; i += 256) d[i] = s[i];
    if (tid < 32) bias_l[tid] = bias_c[wj * 32 + tid];
  }
  __syncthreads();

  const int bg = wave * 32 + col;     // global batch row
  const int jg = wj * 8 + 4 * kh;

  float c_r[4];
  {
    float4 v = *(const float4*)(c0 + (size_t)bg * H_ + jg);
    c_r[0] = v.x; c_r[1] = v.y; c_r[2] = v.z; c_r[3] = v.w;
  }

  const char* wlb = (const char*)Wl;
  const int wrow0 = col * 1536;             // W_hh A-row base (bytes)
  const int wrow1 = 49152 + col * 1536;     // W_ih A-row base

  unsigned* cnt_poll0 = cnt + ((size_t)wave * 8 + (lane & 7)) * 16;   // + t*512
  unsigned* cnt_arr0  = cnt + ((size_t)wave * 8 + (wj & 7)) * 16;     // + (t+1)*512

  float bias_r[16];
  #pragma unroll
  for (int q = 0; q < 16; ++q) bias_r[q] = bias_l[(q & 3) + 8 * (q >> 2) + 4 * kh];

  f32x16 accs[4];
  { // phase X for t=0
    #pragma unroll
    for (int q = 0; q < 16; ++q) {
      accs[0][q] = bias_r[q]; accs[1][q] = 0.f; accs[2][q] = 0.f; accs[3][q] = 0.f;
    }
    const unsigned short* xp = xTb + (size_t)kh * 1024 + bg * 8;
    #pragma unroll
    for (int f = 0; f < 48; ++f) {
      short8v w = *(const short8v*)(wlb + wrow1 + (((2 * f + kh) ^ sw) << 4));
      short8v xv = *(const short8v*)(xp + f * 2048);
      accs[f & 3] = __builtin_amdgcn_mfma_f32_32x32x16_bf16(w, xv, accs[f & 3], 0, 0, 0);
    }
  }

  for (int t = 0; t < T_; ++t) {
    if (t > 0) {
      const unsigned* cw = cnt_poll0 + (size_t)t * 512;
      for (;;) {
        unsigned v = __hip_atomic_load(cw, __ATOMIC_RELAXED, __HIP_MEMORY_SCOPE_AGENT);
        if (__all(v >= 12u)) break;
        __builtin_amdgcn_s_sleep(4);
      }
      asm volatile("" ::: "memory");
    }

    // phase H: 48 coalesced 16B loads (cached if history mode), split drain
    short8v hfrag[48];
    {
      const unsigned short* hp =
          hb + (size_t)(CACHED ? t : (t & 1)) * HSLOT_SH +
          (size_t)kh * 1024 + bg * 8;
      #pragma unroll
      for (int f = 0; f < 48; ++f) {
        if constexpr (CACHED) {
          asm volatile("global_load_dwordx4 %0, %1, off"
                       : "=v"(hfrag[f]) : "v"(hp + f * 2048));
        } else {
          asm volatile("global_load_dwordx4 %0, %1, off sc0 sc1"
                       : "=v"(hfrag[f]) : "v"(hp + f * 2048));
        }
      }
    }
    asm volatile("s_waitcnt vmcnt(24)" ::: "memory");
    __builtin_amdgcn_sched_barrier(0);
    #pragma unroll
    for (int f = 0; f < 24; ++f) {
      short8v w = *(const short8v*)(wlb + wrow0 + (((2 * f + kh) ^ sw) << 4));
      accs[f & 3] = __builtin_amdgcn_mfma_f32_32x32x16_bf16(w, hfrag[f], accs[f & 3], 0, 0, 0);
    }
    asm volatile("s_waitcnt vmcnt(0)" ::: "memory");
    __builtin_amdgcn_sched_barrier(0);
    #pragma unroll
    for (int f = 24; f < 48; ++f) {
      short8v w = *(const short8v*)(wlb + wrow0 + (((2 * f + kh) ^ sw) << 4));
      accs[f & 3] = __builtin_amdgcn_mfma_f32_32x32x16_bf16(w, hfrag[f], accs[f & 3], 0, 0, 0);
    }

    f32x16 g;
    #pragma unroll
    for (int q = 0; q < 16; ++q)
      g[q] = (accs[0][q] + accs[1][q]) + (accs[2][q] + accs[3][q]);

    float hnew[4];
    #pragma unroll
    for (int m = 0; m < 4; ++m) {
      float gi = g[m];
      float gf = g[4 + m];
      float gg = g[8 + m];
      float go = g[12 + m];
      float cn = sigmf(gf) * c_r[m] + sigmf(gi) * tanhf_(gg);
      c_r[m] = cn;
      hnew[m] = sigmf(go) * tanhf_(cn);
    }

    // h exchange: coalesced 8B write-through store (agent scope)
    union { ushort4 s; unsigned long long u; } hv;
    hv.s = (ushort4){f2bf(hnew[0]), f2bf(hnew[1]), f2bf(hnew[2]), f2bf(hnew[3])};
    __hip_atomic_store(
        (unsigned long long*)(hb +
            (size_t)(CACHED ? (t + 1) : ((t + 1) & 1)) * HSLOT_SH +
            (size_t)wj * 1024 + bg * 8 + 4 * kh),
        hv.u, __ATOMIC_RELAXED, __HIP_MEMORY_SCOPE_AGENT);

    // release: wait h-store ack at coherence point, then one arrival add
    asm volatile("s_waitcnt vmcnt(0)" ::: "memory");
    if (lane == 0)
      __hip_atomic_fetch_add(cnt_arr0 + (size_t)(t + 1) * 512, 1u,
                             __ATOMIC_RELAXED, __HIP_MEMORY_SCOPE_AGENT);

    // out stores AFTER the release (off the critical path)
    float4 ov = make_float4(hnew[0], hnew[1], hnew[2], hnew[3]);
    *(float4*)(out + ((size_t)bg * T_ + t) * H_ + jg) = ov;
    if (t == T_ - 1) {
      *(float4*)(hT + (size_t)bg * H_ + jg) = ov;
      float4 cv = make_float4(c_r[0], c_r[1], c_r[2], c_r[3]);
      *(float4*)(cT + (size_t)bg * H_ + jg) = cv;
    }

    // phase X for t+1 (cached coalesced loads), in the shadow of the wait
    if (t + 1 < T_) {
      #pragma unroll
      for (int q = 0; q < 16; ++q) {
        accs[0][q] = bias_r[q]; accs[1][q] = 0.f; accs[2][q] = 0.f; accs[3][q] = 0.f;
      }
      const unsigned short* xp =
          xTb + (size_t)(t + 1) * 98304 + (size_t)kh * 1024 + bg * 8;
      #pragma unroll
      for (int f = 0; f < 48; ++f) {
        short8v w = *(const short8v*)(wlb + wrow1 + (((2 * f + kh) ^ sw) << 4));
        short8v xv = *(const short8v*)(xp + f * 2048);
        accs[f & 3] = __builtin_amdgcn_mfma_f32_32x32x16_bf16(w, xv, accs[f & 3], 0, 0, 0);
      }
    }
  }
}

extern "C" void kernel_launch(void* const* d_in, const int* in_sizes, int n_in,
                              void* d_out, int out_size, void* d_ws, size_t ws_size,
                              hipStream_t stream) {
  const float* x   = (const float*)d_in[0];
  const float* h0  = (const float*)d_in[1];
  const float* c0  = (const float*)d_in[2];
  const float* wih = (const float*)d_in[3];
  const float* whh = (const float*)d_in[4];
  const float* bih = (const float*)d_in[5];
  const float* bhh = (const float*)d_in[6];

  float* out = (float*)d_out;
  float* hT  = out + (size_t)B_ * T_ * H_;
  float* cT  = hT + (size_t)B_ * H_;

  const size_t need_full = CNT_BYTES + HB_FULL + BIAS_B + WC_B + XT_B;  // ~414.5 MB
  const size_t need_min  = CNT_BYTES + HB_MIN  + BIAS_B + WC_B + XT_B;  // ~213.3 MB
  const bool cached = (ws_size >= need_full);
  if (ws_size < need_min) return;  // visible failure instead of OOB corruption

  char* p = (char*)d_ws;
  unsigned*       cnt   = (unsigned*)p;        p += CNT_BYTES;
  unsigned short* hb    = (unsigned short*)p;  p += (cached ? HB_FULL : HB_MIN);
  float*          biasc = (float*)p;           p += BIAS_B;
  unsigned short* Wc    = (unsigned short*)p;  p += WC_B;
  unsigned short* xTp   = (unsigned short*)p;

  k_xT<<<dim3(T_), dim3(256), 0, stream>>>(x, xTp);
  k_prep_w<<<dim3(589824 / 256), dim3(256), 0, stream>>>(wih, whh, Wc);
  k_prep_s<<<dim3((B_ * H_) / 256), dim3(256), 0, stream>>>(h0, bih, bhh, hb, biasc, cnt);
  if (cached)
    k_lstm<true><<<dim3(NWG), dim3(256), 0, stream>>>(xTp, Wc, biasc, c0, hb, cnt, out, hT, cT);
  else
    k_lstm<false><<<dim3(NWG), dim3(256), 0, stream>>>(xTp, Wc, biasc, c0, hb, cnt, out, hT, cT);
}

// Round 6
// 20829.556 us; speedup vs baseline: 1.1158x; 1.1106x over previous
//
#include <hip/hip_runtime.h>
#include <hip/hip_bf16.h>

// LSTM: B=128, T=1024, D=H=768.
// R6: crush the poll request rate. Two-level arrival counters:
//   subs[t][band][8] (12 waves each, 32B padded) -> 12th arrival bumps ONE
//   global final[t] line. Consumers: wave 0 only, all lanes poll the SAME
//   line (1 fabric request/iter/WG), s_sleep(8), then __syncthreads.
// Also dispatch k_flow (same body, wait compiled out) as a diagnostic to
// bisect wait-vs-flow cost in the rocprof table; its state is re-prepped
// before the real k_lstm and its out writes are fully overwritten.

typedef __attribute__((ext_vector_type(8))) short short8v;   // 8 bf16 = 4 VGPR
typedef __attribute__((ext_vector_type(16))) float f32x16;   // 32x32 acc

constexpr int B_ = 128, T_ = 1024, D_ = 768, H_ = 768;
constexpr int NWG = 96;          // j-groups (8 h-cols each)

// cnt region: subs u32[1025][4][8][8] (=262400 u32), then final u32[1025][16]
constexpr size_t SUBS_U32  = 1025ull * 4 * 8 * 8;      // 262400
constexpr size_t CNT_U32   = 1025ull * 4 * 8 * 16;     // zero extent (covers both)
constexpr size_t CNT_BYTES = 2101248;
constexpr size_t HSLOT_SH  = 96ull * 128 * 8;          // 98304 shorts = 196608 B
constexpr size_t HB_OFF    = CNT_BYTES;                // 2 slots = 393216 B
constexpr size_t BIAS_OFF  = HB_OFF + 393216;
constexpr size_t WC_OFF    = BIAS_OFF + 12288;
constexpr size_t XT_OFF    = WC_OFF + 9437184;
constexpr size_t WS_NEED   = XT_OFF + 201326592;       // 213270528 B (known-good)

__device__ __forceinline__ unsigned short f2bf(float f) {
  union { float f; unsigned u; } v; v.f = f;
  unsigned r = v.u + 0x7FFF + ((v.u >> 16) & 1);       // RNE
  return (unsigned short)(r >> 16);
}
__device__ __forceinline__ float sigmf(float x) { return 1.0f / (1.0f + __expf(-x)); }
__device__ __forceinline__ float tanhf_(float x) {
  float ax = fabsf(x);
  float e = __expf(-2.0f * ax);
  float t = (1.0f - e) / (1.0f + e);
  return copysignf(t, x);
}

// ---------------- P1: x -> xTb[t][kb][b][ko] bf16, LDS-tiled transpose ----
__global__ void k_xT(const float* __restrict__ x, unsigned short* __restrict__ xTb) {
  __shared__ float tile[16][776];
  const int t = blockIdx.x;
  const int tid = threadIdx.x;
  for (int chunk = 0; chunk < 8; ++chunk) {
    #pragma unroll
    for (int i = 0; i < 12; ++i) {
      int id = i * 256 + tid;
      int bl = id / 192, d4 = id % 192;
      int b = chunk * 16 + bl;
      float4 v = *(const float4*)(x + ((size_t)b * T_ + t) * D_ + d4 * 4);
      *(float4*)&tile[bl][d4 * 4] = v;
    }
    __syncthreads();
    #pragma unroll
    for (int i = 0; i < 6; ++i) {
      int id = i * 256 + tid;
      int kb = id >> 4, bl = id & 15;
      int b = chunk * 16 + bl;
      const float* src = &tile[bl][kb * 8];
      unsigned short tmp[8];
      #pragma unroll
      for (int k = 0; k < 8; ++k) tmp[k] = f2bf(src[k]);
      *(short8v*)(xTb + (((size_t)t * 96 + kb) * 128 + b) * 8) = *(short8v*)tmp;
    }
    __syncthreads();
  }
}

// ---------------- P2: weight slices, swizzled ----------------------------
__global__ void k_prep_w(const float* __restrict__ wih, const float* __restrict__ whh,
                         unsigned short* __restrict__ Wc) {
  int id  = blockIdx.x * 256 + threadIdx.x;            // exactly 589824
  int wj  = id / 6144;
  int rem = id - wj * 6144;
  int src = rem / 3072; rem -= src * 3072;
  int r   = rem / 96;
  int kcp = rem - r * 96;
  int kc  = kcp ^ (r & 15);
  int grow = (r >> 3) * H_ + wj * 8 + (r & 7);
  const float* W = (src == 0) ? whh : wih;
  const float* p = W + (size_t)grow * D_ + kc * 8;
  float4 v0 = *(const float4*)p;
  float4 v1 = *(const float4*)(p + 4);
  ushort4 o0 = {f2bf(v0.x), f2bf(v0.y), f2bf(v0.z), f2bf(v0.w)};
  ushort4 o1 = {f2bf(v1.x), f2bf(v1.y), f2bf(v1.z), f2bf(v1.w)};
  *(ushort4*)(Wc + (size_t)id * 8)     = o0;
  *(ushort4*)(Wc + (size_t)id * 8 + 4) = o1;
}

// ---------------- P3: bias, h0 -> blocked bf16 slot0, zero counters ------
__global__ void k_prep_s(const float* __restrict__ h0,
                         const float* __restrict__ bih, const float* __restrict__ bhh,
                         unsigned short* __restrict__ hb, float* __restrict__ bias_c,
                         unsigned* __restrict__ cnt) {
  int id = blockIdx.x * 256 + threadIdx.x;             // exactly 98304
  int b = id / 768, j = id - b * 768;
  hb[(size_t)(j >> 3) * 1024 + b * 8 + (j & 7)] = f2bf(h0[id]);
  if (id < 3072) {
    int wj = id >> 5, r = id & 31;
    int grow = (r >> 3) * H_ + wj * 8 + (r & 7);
    bias_c[id] = bih[grow] + bhh[grow];
  }
  for (size_t i = id; i < CNT_U32; i += 98304) cnt[i] = 0;
}

// ---------------- main recurrent body (WAIT=false: diagnostic flow) ------
template <bool WAIT>
__device__ __forceinline__ void lstm_body(
    const unsigned short* __restrict__ xTb,
    const unsigned short* __restrict__ Wc,
    const float* __restrict__ bias_c,
    const float* __restrict__ c0,
    unsigned short* __restrict__ hb,   // [2][96][128][8] bf16
    unsigned* cnt,                     // subs + final
    float* __restrict__ out,
    float* __restrict__ hT,
    float* __restrict__ cT) {
  __shared__ __align__(16) unsigned short Wl[2 * 32 * 768];   // 96 KB
  __shared__ float bias_l[32];

  const int wj   = blockIdx.x;
  const int tid  = threadIdx.x;
  const int wave = tid >> 6;          // band: batch rows wave*32..+32
  const int lane = tid & 63;
  const int col  = lane & 31;
  const int kh   = lane >> 5;
  const int sw   = col & 15;

  unsigned* subs   = cnt;                         // [1025][4][8][8] u32
  unsigned* finalc = cnt + SUBS_U32;              // [1025][16] u32

  {
    const short8v* s = (const short8v*)(Wc + (size_t)wj * 49152);
    short8v* d = (short8v*)Wl;
    for (int i = tid; i < 6144; i += 256) d[i] = s[i];
    if (tid < 32) bias_l[tid] = bias_c[wj * 32 + tid];
  }
  __syncthreads();

  const int bg = wave * 32 + col;     // global batch row
  const int jg = wj * 8 + 4 * kh;

  float c_r[4];
  {
    float4 v = *(const float4*)(c0 + (size_t)bg * H_ + jg);
    c_r[0] = v.x; c_r[1] = v.y; c_r[2] = v.z; c_r[3] = v.w;
  }

  const char* wlb = (const char*)Wl;
  const int wrow0 = col * 1536;             // W_hh A-row base (bytes)
  const int wrow1 = 49152 + col * 1536;     // W_ih A-row base

  float bias_r[16];
  #pragma unroll
  for (int q = 0; q < 16; ++q) bias_r[q] = bias_l[(q & 3) + 8 * (q >> 2) + 4 * kh];

  f32x16 accs[4];
  { // phase X for t=0
    #pragma unroll
    for (int q = 0; q < 16; ++q) {
      accs[0][q] = bias_r[q]; accs[1][q] = 0.f; accs[2][q] = 0.f; accs[3][q] = 0.f;
    }
    const unsigned short* xp = xTb + (size_t)kh * 1024 + bg * 8;
    #pragma unroll
    for (int f = 0; f < 48; ++f) {
      short8v w = *(const short8v*)(wlb + wrow1 + (((2 * f + kh) ^ sw) << 4));
      short8v xv = *(const short8v*)(xp + f * 2048);
      accs[f & 3] = __builtin_amdgcn_mfma_f32_32x32x16_bf16(w, xv, accs[f & 3], 0, 0, 0);
    }
  }

  for (int t = 0; t < T_; ++t) {
    if (t > 0) {
      if (WAIT && wave == 0) {
        // single-line poll: all lanes same address -> 1 fabric req/iter
        const unsigned* fp = finalc + (size_t)t * 16;
        for (;;) {
          unsigned v = __hip_atomic_load(fp, __ATOMIC_RELAXED, __HIP_MEMORY_SCOPE_AGENT);
          if (v >= 32u) break;
          __builtin_amdgcn_s_sleep(8);
        }
      }
      __syncthreads();
      asm volatile("" ::: "memory");
    }

    // phase H: 48 coalesced uncached 16B loads, split-drain MFMA
    short8v hfrag[48];
    {
      const unsigned short* hp =
          hb + (size_t)(t & 1) * HSLOT_SH + (size_t)kh * 1024 + bg * 8;
      #pragma unroll
      for (int f = 0; f < 48; ++f) {
        asm volatile("global_load_dwordx4 %0, %1, off sc0 sc1"
                     : "=v"(hfrag[f]) : "v"(hp + f * 2048));
      }
    }
    asm volatile("s_waitcnt vmcnt(24)" ::: "memory");
    __builtin_amdgcn_sched_barrier(0);
    #pragma unroll
    for (int f = 0; f < 24; ++f) {
      short8v w = *(const short8v*)(wlb + wrow0 + (((2 * f + kh) ^ sw) << 4));
      accs[f & 3] = __builtin_amdgcn_mfma_f32_32x32x16_bf16(w, hfrag[f], accs[f & 3], 0, 0, 0);
    }
    asm volatile("s_waitcnt vmcnt(0)" ::: "memory");
    __builtin_amdgcn_sched_barrier(0);
    #pragma unroll
    for (int f = 24; f < 48; ++f) {
      short8v w = *(const short8v*)(wlb + wrow0 + (((2 * f + kh) ^ sw) << 4));
      accs[f & 3] = __builtin_amdgcn_mfma_f32_32x32x16_bf16(w, hfrag[f], accs[f & 3], 0, 0, 0);
    }

    f32x16 g;
    #pragma unroll
    for (int q = 0; q < 16; ++q)
      g[q] = (accs[0][q] + accs[1][q]) + (accs[2][q] + accs[3][q]);

    float hnew[4];
    #pragma unroll
    for (int m = 0; m < 4; ++m) {
      float gi = g[m];
      float gf = g[4 + m];
      float gg = g[8 + m];
      float go = g[12 + m];
      float cn = sigmf(gf) * c_r[m] + sigmf(gi) * tanhf_(gg);
      c_r[m] = cn;
      hnew[m] = sigmf(go) * tanhf_(cn);
    }

    // h exchange: coalesced 8B write-through store (agent scope)
    union { ushort4 s; unsigned long long u; } hv;
    hv.s = (ushort4){f2bf(hnew[0]), f2bf(hnew[1]), f2bf(hnew[2]), f2bf(hnew[3])};
    __hip_atomic_store(
        (unsigned long long*)(hb + (size_t)((t + 1) & 1) * HSLOT_SH +
                              (size_t)wj * 1024 + bg * 8 + 4 * kh),
        hv.u, __ATOMIC_RELAXED, __HIP_MEMORY_SCOPE_AGENT);

    // release: h stores acked, then two-level arrival
    asm volatile("s_waitcnt vmcnt(0)" ::: "memory");
    if (lane == 0) {
      unsigned old = __hip_atomic_fetch_add(
          subs + ((size_t)(t + 1) * 4 + wave) * 8 + (wj & 7), 1u,
          __ATOMIC_RELAXED, __HIP_MEMORY_SCOPE_AGENT);
      if (old == 11u)
        __hip_atomic_fetch_add(finalc + (size_t)(t + 1) * 16, 1u,
                               __ATOMIC_RELAXED, __HIP_MEMORY_SCOPE_AGENT);
    }

    // out stores AFTER the release (off the critical path)
    float4 ov = make_float4(hnew[0], hnew[1], hnew[2], hnew[3]);
    *(float4*)(out + ((size_t)bg * T_ + t) * H_ + jg) = ov;
    if (t == T_ - 1) {
      *(float4*)(hT + (size_t)bg * H_ + jg) = ov;
      float4 cv = make_float4(c_r[0], c_r[1], c_r[2], c_r[3]);
      *(float4*)(cT + (size_t)bg * H_ + jg) = cv;
    }

    // phase X for t+1 (cached coalesced loads), in the shadow of the wait
    if (t + 1 < T_) {
      #pragma unroll
      for (int q = 0; q < 16; ++q) {
        accs[0][q] = bias_r[q]; accs[1][q] = 0.f; accs[2][q] = 0.f; accs[3][q] = 0.f;
      }
      const unsigned short* xp =
          xTb + (size_t)(t + 1) * 98304 + (size_t)kh * 1024 + bg * 8;
      #pragma unroll
      for (int f = 0; f < 48; ++f) {
        short8v w = *(const short8v*)(wlb + wrow1 + (((2 * f + kh) ^ sw) << 4));
        short8v xv = *(const short8v*)(xp + f * 2048);
        accs[f & 3] = __builtin_amdgcn_mfma_f32_32x32x16_bf16(w, xv, accs[f & 3], 0, 0, 0);
      }
    }
  }
}

__launch_bounds__(256, 1)
__global__ void k_lstm(const unsigned short* __restrict__ xTb,
                       const unsigned short* __restrict__ Wc,
                       const float* __restrict__ bias_c,
                       const float* __restrict__ c0,
                       unsigned short* __restrict__ hb, unsigned* cnt,
                       float* __restrict__ out, float* __restrict__ hT,
                       float* __restrict__ cT) {
  lstm_body<true>(xTb, Wc, bias_c, c0, hb, cnt, out, hT, cT);
}

// diagnostic: identical flow, wait compiled out (timing bisection only)
__launch_bounds__(256, 1)
__global__ void k_flow(const unsigned short* __restrict__ xTb,
                       const unsigned short* __restrict__ Wc,
                       const float* __restrict__ bias_c,
                       const float* __restrict__ c0,
                       unsigned short* __restrict__ hb, unsigned* cnt,
                       float* __restrict__ out, float* __restrict__ hT,
                       float* __restrict__ cT) {
  lstm_body<false>(xTb, Wc, bias_c, c0, hb, cnt, out, hT, cT);
}

extern "C" void kernel_launch(void* const* d_in, const int* in_sizes, int n_in,
                              void* d_out, int out_size, void* d_ws, size_t ws_size,
                              hipStream_t stream) {
  const float* x   = (const float*)d_in[0];
  const float* h0  = (const float*)d_in[1];
  const float* c0  = (const float*)d_in[2];
  const float* wih = (const float*)d_in[3];
  const float* whh = (const float*)d_in[4];
  const float* bih = (const float*)d_in[5];
  const float* bhh = (const float*)d_in[6];

  float* out = (float*)d_out;
  float* hT  = out + (size_t)B_ * T_ * H_;
  float* cT  = hT + (size_t)B_ * H_;

  if (ws_size < WS_NEED) return;  // visible failure instead of OOB corruption

  char* ws = (char*)d_ws;
  unsigned*       cnt   = (unsigned*)(ws);
  unsigned short* hb    = (unsigned short*)(ws + HB_OFF);
  float*          biasc = (float*)(ws + BIAS_OFF);
  unsigned short* Wc    = (unsigned short*)(ws + WC_OFF);
  unsigned short* xTp   = (unsigned short*)(ws + XT_OFF);

  k_xT<<<dim3(T_), dim3(256), 0, stream>>>(x, xTp);
  k_prep_w<<<dim3(589824 / 256), dim3(256), 0, stream>>>(wih, whh, Wc);
  k_prep_s<<<dim3((B_ * H_) / 256), dim3(256), 0, stream>>>(h0, bih, bhh, hb, biasc, cnt);

  // diagnostic flow-only pass (state re-prepped below; out fully overwritten)
  k_flow<<<dim3(NWG), dim3(256), 0, stream>>>(xTp, Wc, biasc, c0, hb, cnt, out, hT, cT);

  k_prep_s<<<dim3((B_ * H_) / 256), dim3(256), 0, stream>>>(h0, bih, bhh, hb, biasc, cnt);
  k_lstm<<<dim3(NWG), dim3(256), 0, stream>>>(xTp, Wc, biasc, c0, hb, cnt, out, hT, cT);
}

// Round 8
// 13334.128 us; speedup vs baseline: 1.7430x; 1.5621x over previous
//
#include <hip/hip_runtime.h>
#include <hip/hip_bf16.h>

// LSTM: B=128, T=1024, D=H=768.
// R8: L2-dedup of the h broadcast WITHOUT relay/XCC_ID (R7 hung on intra-XCD
// flag visibility). Per step each WG: poll final[t] (MALL, proven R6) ->
// buffer_inv sc1 (invalidate clean L2 lines; dirty survive; vmcnt-tracked)
// -> plain sc0 h loads (L1-bypass, L2-ALLOCATING). First reader per XCD
// fetches fresh h from MALL, 11 others hit L2: fabric h traffic /12.
// Freshness: nobody touches slot t&1 before final[t]; any post-inv L2 fill
// comes from the current MALL copy. Producers unchanged (sc1 write-through +
// vmcnt(0) + two-level arrival counters).

typedef __attribute__((ext_vector_type(8))) short short8v;   // 8 bf16 = 4 VGPR
typedef __attribute__((ext_vector_type(16))) float f32x16;   // 32x32 acc

constexpr int B_ = 128, T_ = 1024, D_ = 768, H_ = 768;
constexpr int NWG = 96;          // j-groups (8 h-cols each)

// cnt region: subs u32[1025][4][8][8] (=262400 u32), then final u32[1025][16]
constexpr size_t SUBS_U32  = 1025ull * 4 * 8 * 8;      // 262400
constexpr size_t CNT_U32   = 1025ull * 4 * 8 * 16;     // zeroed extent
constexpr size_t CNT_BYTES = 2101248;
constexpr size_t HSLOT_SH  = 96ull * 128 * 8;          // 98304 shorts = 196608 B
constexpr size_t HB_OFF    = CNT_BYTES;                // 2 slots = 393216 B
constexpr size_t BIAS_OFF  = HB_OFF + 393216;
constexpr size_t WC_OFF    = BIAS_OFF + 12288;
constexpr size_t XT_OFF    = WC_OFF + 9437184;
constexpr size_t WS_NEED   = XT_OFF + 201326592;       // 213270528 B (known-good)

__device__ __forceinline__ unsigned short f2bf(float f) {
  union { float f; unsigned u; } v; v.f = f;
  unsigned r = v.u + 0x7FFF + ((v.u >> 16) & 1);       // RNE
  return (unsigned short)(r >> 16);
}
__device__ __forceinline__ float sigmf(float x) { return 1.0f / (1.0f + __expf(-x)); }
__device__ __forceinline__ float tanhf_(float x) {
  float ax = fabsf(x);
  float e = __expf(-2.0f * ax);
  float t = (1.0f - e) / (1.0f + e);
  return copysignf(t, x);
}

// ---------------- P1: x -> xTb[t][kb][b][ko] bf16, LDS-tiled transpose ----
__global__ void k_xT(const float* __restrict__ x, unsigned short* __restrict__ xTb) {
  __shared__ float tile[16][776];
  const int t = blockIdx.x;
  const int tid = threadIdx.x;
  for (int chunk = 0; chunk < 8; ++chunk) {
    #pragma unroll
    for (int i = 0; i < 12; ++i) {
      int id = i * 256 + tid;
      int bl = id / 192, d4 = id % 192;
      int b = chunk * 16 + bl;
      float4 v = *(const float4*)(x + ((size_t)b * T_ + t) * D_ + d4 * 4);
      *(float4*)&tile[bl][d4 * 4] = v;
    }
    __syncthreads();
    #pragma unroll
    for (int i = 0; i < 6; ++i) {
      int id = i * 256 + tid;
      int kb = id >> 4, bl = id & 15;
      int b = chunk * 16 + bl;
      const float* src = &tile[bl][kb * 8];
      unsigned short tmp[8];
      #pragma unroll
      for (int k = 0; k < 8; ++k) tmp[k] = f2bf(src[k]);
      *(short8v*)(xTb + (((size_t)t * 96 + kb) * 128 + b) * 8) = *(short8v*)tmp;
    }
    __syncthreads();
  }
}

// ---------------- P2: weight slices, swizzled ----------------------------
__global__ void k_prep_w(const float* __restrict__ wih, const float* __restrict__ whh,
                         unsigned short* __restrict__ Wc) {
  int id  = blockIdx.x * 256 + threadIdx.x;            // exactly 589824
  int wj  = id / 6144;
  int rem = id - wj * 6144;
  int src = rem / 3072; rem -= src * 3072;
  int r   = rem / 96;
  int kcp = rem - r * 96;
  int kc  = kcp ^ (r & 15);
  int grow = (r >> 3) * H_ + wj * 8 + (r & 7);
  const float* W = (src == 0) ? whh : wih;
  const float* p = W + (size_t)grow * D_ + kc * 8;
  float4 v0 = *(const float4*)p;
  float4 v1 = *(const float4*)(p + 4);
  ushort4 o0 = {f2bf(v0.x), f2bf(v0.y), f2bf(v0.z), f2bf(v0.w)};
  ushort4 o1 = {f2bf(v1.x), f2bf(v1.y), f2bf(v1.z), f2bf(v1.w)};
  *(ushort4*)(Wc + (size_t)id * 8)     = o0;
  *(ushort4*)(Wc + (size_t)id * 8 + 4) = o1;
}

// ---------------- P3: bias, h0 -> blocked bf16 slot0, zero counters ------
__global__ void k_prep_s(const float* __restrict__ h0,
                         const float* __restrict__ bih, const float* __restrict__ bhh,
                         unsigned short* __restrict__ hb, float* __restrict__ bias_c,
                         unsigned* __restrict__ cnt) {
  int id = blockIdx.x * 256 + threadIdx.x;             // exactly 98304
  int b = id / 768, j = id - b * 768;
  hb[(size_t)(j >> 3) * 1024 + b * 8 + (j & 7)] = f2bf(h0[id]);
  if (id < 3072) {
    int wj = id >> 5, r = id & 31;
    int grow = (r >> 3) * H_ + wj * 8 + (r & 7);
    bias_c[id] = bih[grow] + bhh[grow];
  }
  for (size_t i = id; i < CNT_U32; i += 98304) cnt[i] = 0;
}

// ---------------- main recurrent kernel ----------------------------------
__launch_bounds__(256, 1)
__global__ void k_lstm(const unsigned short* __restrict__ xTb,
                       const unsigned short* __restrict__ Wc,
                       const float* __restrict__ bias_c,
                       const float* __restrict__ c0,
                       unsigned short* __restrict__ hb,   // [2][96][128][8] bf16
                       unsigned* cnt,
                       float* __restrict__ out,
                       float* __restrict__ hT,
                       float* __restrict__ cT) {
  __shared__ __align__(16) unsigned short Wl[2 * 32 * 768];   // 96 KB
  __shared__ float bias_l[32];

  const int wj   = blockIdx.x;
  const int tid  = threadIdx.x;
  const int wave = tid >> 6;          // band: batch rows wave*32..+32
  const int lane = tid & 63;
  const int col  = lane & 31;
  const int kh   = lane >> 5;
  const int sw   = col & 15;

  unsigned* subs   = cnt;                         // [1025][4][8][8] u32
  unsigned* finalc = cnt + SUBS_U32;              // [1025][16] u32

  {
    const short8v* s = (const short8v*)(Wc + (size_t)wj * 49152);
    short8v* d = (short8v*)Wl;
    for (int i = tid; i < 6144; i += 256) d[i] = s[i];
    if (tid < 32) bias_l[tid] = bias_c[wj * 32 + tid];
  }
  __syncthreads();

  const int bg = wave * 32 + col;     // global batch row
  const int jg = wj * 8 + 4 * kh;

  float c_r[4];
  {
    float4 v = *(const float4*)(c0 + (size_t)bg * H_ + jg);
    c_r[0] = v.x; c_r[1] = v.y; c_r[2] = v.z; c_r[3] = v.w;
  }

  const char* wlb = (const char*)Wl;
  const int wrow0 = col * 1536;             // W_hh A-row base (bytes)
  const int wrow1 = 49152 + col * 1536;     // W_ih A-row base

  float bias_r[16];
  #pragma unroll
  for (int q = 0; q < 16; ++q) bias_r[q] = bias_l[(q & 3) + 8 * (q >> 2) + 4 * kh];

  f32x16 accs[4];
  { // phase X for t=0
    #pragma unroll
    for (int q = 0; q < 16; ++q) {
      accs[0][q] = bias_r[q]; accs[1][q] = 0.f; accs[2][q] = 0.f; accs[3][q] = 0.f;
    }
    const unsigned short* xp = xTb + (size_t)kh * 1024 + bg * 8;
    #pragma unroll
    for (int f = 0; f < 48; ++f) {
      short8v w = *(const short8v*)(wlb + wrow1 + (((2 * f + kh) ^ sw) << 4));
      short8v xv = *(const short8v*)(xp + f * 2048);
      accs[f & 3] = __builtin_amdgcn_mfma_f32_32x32x16_bf16(w, xv, accs[f & 3], 0, 0, 0);
    }
  }

  for (int t = 0; t < T_; ++t) {
    if (t > 0) {
      if (wave == 0) {
        // single-line MALL poll (all lanes same address)
        const unsigned* fp = finalc + (size_t)t * 16;
        for (;;) {
          unsigned v = __hip_atomic_load(fp, __ATOMIC_RELAXED, __HIP_MEMORY_SCOPE_AGENT);
          if (v >= 32u) break;
          __builtin_amdgcn_s_sleep(8);
        }
      }
      __syncthreads();
      // acquire: invalidate clean L2 lines so cached h reads can't be stale.
      // Dirty lines (our out stores) survive; vmcnt-tracked.
      asm volatile("buffer_inv sc1\n\ts_waitcnt vmcnt(0)" ::: "memory");
    }

    // phase H: 48 coalesced sc0 loads (L1-bypass, L2-ALLOCATING -> XCD dedup)
    short8v hfrag[48];
    {
      const unsigned short* hp =
          hb + (size_t)(t & 1) * HSLOT_SH + (size_t)kh * 1024 + bg * 8;
      #pragma unroll
      for (int f = 0; f < 48; ++f) {
        asm volatile("global_load_dwordx4 %0, %1, off sc0"
                     : "=v"(hfrag[f]) : "v"(hp + f * 2048));
      }
    }
    asm volatile("s_waitcnt vmcnt(24)" ::: "memory");
    __builtin_amdgcn_sched_barrier(0);
    #pragma unroll
    for (int f = 0; f < 24; ++f) {
      short8v w = *(const short8v*)(wlb + wrow0 + (((2 * f + kh) ^ sw) << 4));
      accs[f & 3] = __builtin_amdgcn_mfma_f32_32x32x16_bf16(w, hfrag[f], accs[f & 3], 0, 0, 0);
    }
    asm volatile("s_waitcnt vmcnt(0)" ::: "memory");
    __builtin_amdgcn_sched_barrier(0);
    #pragma unroll
    for (int f = 24; f < 48; ++f) {
      short8v w = *(const short8v*)(wlb + wrow0 + (((2 * f + kh) ^ sw) << 4));
      accs[f & 3] = __builtin_amdgcn_mfma_f32_32x32x16_bf16(w, hfrag[f], accs[f & 3], 0, 0, 0);
    }

    f32x16 g;
    #pragma unroll
    for (int q = 0; q < 16; ++q)
      g[q] = (accs[0][q] + accs[1][q]) + (accs[2][q] + accs[3][q]);

    float hnew[4];
    #pragma unroll
    for (int m = 0; m < 4; ++m) {
      float gi = g[m];
      float gf = g[4 + m];
      float gg = g[8 + m];
      float go = g[12 + m];
      float cn = sigmf(gf) * c_r[m] + sigmf(gi) * tanhf_(gg);
      c_r[m] = cn;
      hnew[m] = sigmf(go) * tanhf_(cn);
    }

    // h exchange: coalesced 8B write-through store (agent scope -> MALL)
    union { ushort4 s; unsigned long long u; } hv;
    hv.s = (ushort4){f2bf(hnew[0]), f2bf(hnew[1]), f2bf(hnew[2]), f2bf(hnew[3])};
    __hip_atomic_store(
        (unsigned long long*)(hb + (size_t)((t + 1) & 1) * HSLOT_SH +
                              (size_t)wj * 1024 + bg * 8 + 4 * kh),
        hv.u, __ATOMIC_RELAXED, __HIP_MEMORY_SCOPE_AGENT);

    // release: h stores acked at MALL, then two-level arrival
    asm volatile("s_waitcnt vmcnt(0)" ::: "memory");
    if (lane == 0) {
      unsigned old = __hip_atomic_fetch_add(
          subs + ((size_t)(t + 1) * 4 + wave) * 8 + (wj & 7), 1u,
          __ATOMIC_RELAXED, __HIP_MEMORY_SCOPE_AGENT);
      if (old == 11u)
        __hip_atomic_fetch_add(finalc + (size_t)(t + 1) * 16, 1u,
                               __ATOMIC_RELAXED, __HIP_MEMORY_SCOPE_AGENT);
    }

    // out stores AFTER the release (off the critical path)
    float4 ov = make_float4(hnew[0], hnew[1], hnew[2], hnew[3]);
    *(float4*)(out + ((size_t)bg * T_ + t) * H_ + jg) = ov;
    if (t == T_ - 1) {
      *(float4*)(hT + (size_t)bg * H_ + jg) = ov;
      float4 cv = make_float4(c_r[0], c_r[1], c_r[2], c_r[3]);
      *(float4*)(cT + (size_t)bg * H_ + jg) = cv;
    }

    // phase X for t+1 (cached coalesced loads), in the shadow of the wait
    if (t + 1 < T_) {
      #pragma unroll
      for (int q = 0; q < 16; ++q) {
        accs[0][q] = bias_r[q]; accs[1][q] = 0.f; accs[2][q] = 0.f; accs[3][q] = 0.f;
      }
      const unsigned short* xp =
          xTb + (size_t)(t + 1) * 98304 + (size_t)kh * 1024 + bg * 8;
      #pragma unroll
      for (int f = 0; f < 48; ++f) {
        short8v w = *(const short8v*)(wlb + wrow1 + (((2 * f + kh) ^ sw) << 4));
        short8v xv = *(const short8v*)(xp + f * 2048);
        accs[f & 3] = __builtin_amdgcn_mfma_f32_32x32x16_bf16(w, xv, accs[f & 3], 0, 0, 0);
      }
    }
  }
}

extern "C" void kernel_launch(void* const* d_in, const int* in_sizes, int n_in,
                              void* d_out, int out_size, void* d_ws, size_t ws_size,
                              hipStream_t stream) {
  const float* x   = (const float*)d_in[0];
  const float* h0  = (const float*)d_in[1];
  const float* c0  = (const float*)d_in[2];
  const float* wih = (const float*)d_in[3];
  const float* whh = (const float*)d_in[4];
  const float* bih = (const float*)d_in[5];
  const float* bhh = (const float*)d_in[6];

  float* out = (float*)d_out;
  float* hT  = out + (size_t)B_ * T_ * H_;
  float* cT  = hT + (size_t)B_ * H_;

  if (ws_size < WS_NEED) return;  // visible failure instead of OOB corruption

  char* ws = (char*)d_ws;
  unsigned*       cnt   = (unsigned*)(ws);
  unsigned short* hb    = (unsigned short*)(ws + HB_OFF);
  float*          biasc = (float*)(ws + BIAS_OFF);
  unsigned short* Wc    = (unsigned short*)(ws + WC_OFF);
  unsigned short* xTp   = (unsigned short*)(ws + XT_OFF);

  k_xT<<<dim3(T_), dim3(256), 0, stream>>>(x, xTp);
  k_prep_w<<<dim3(589824 / 256), dim3(256), 0, stream>>>(wih, whh, Wc);
  k_prep_s<<<dim3((B_ * H_) / 256), dim3(256), 0, stream>>>(h0, bih, bhh, hb, biasc, cnt);
  k_lstm<<<dim3(NWG), dim3(256), 0, stream>>>(xTp, Wc, biasc, c0, hb, cnt, out, hT, cT);
}

// Round 9
// 11052.584 us; speedup vs baseline: 2.1028x; 1.2064x over previous
//
#include <hip/hip_runtime.h>
#include <hip/hip_bf16.h>

// LSTM: B=128, T=1024, D=H=768.
// R9: h-state REPLICATION x4 to spread MALL slice load. R8's buffer_inv
// regressed (whole-L2 inv per WG per step thrashes neighbors + xT). R6 flow
// analysis: 18.9MB/step sc1 h-reads of a single 196KB region = 96 readers
// per cache line -> suspected MALL slice hotspot. Producers now write h to
// 4 replicas (sc1 write-through, +24B/lane/step); reader WG wj reads replica
// wj&3 (24 readers/replica). Single-level arrival counter (one add per WG,
// after ALL waves' stores are acked via vmcnt(0)+barrier). Protocol
// otherwise identical to R6.

typedef __attribute__((ext_vector_type(8))) short short8v;   // 8 bf16 = 4 VGPR
typedef __attribute__((ext_vector_type(16))) float f32x16;   // 32x32 acc

constexpr int B_ = 128, T_ = 1024, D_ = 768, H_ = 768;
constexpr int NWG = 96;          // j-groups (8 h-cols each)
constexpr int NREP = 4;          // h replicas

constexpr size_t FINAL_U32 = 1025ull * 16;             // final[t][16] u32
constexpr size_t HSLOT_SH  = 96ull * 128 * 8;          // 98304 shorts = 196608 B
constexpr size_t HREP_OFF  = 65600;                    // FINAL bytes (16B aligned)
constexpr size_t HREP_B    = (size_t)NREP * 2 * 196608;      // 1,572,864
constexpr size_t BIAS_OFF  = HREP_OFF + HREP_B;        // 1,638,464
constexpr size_t WC_OFF    = BIAS_OFF + 12288;         // 1,650,752
constexpr size_t XT_OFF    = WC_OFF + 9437184;         // 11,087,936
constexpr size_t WS_NEED   = XT_OFF + 201326592;       // 212,414,528 (< 213,270,528 known-good)

__device__ __forceinline__ unsigned short f2bf(float f) {
  union { float f; unsigned u; } v; v.f = f;
  unsigned r = v.u + 0x7FFF + ((v.u >> 16) & 1);       // RNE
  return (unsigned short)(r >> 16);
}
__device__ __forceinline__ float sigmf(float x) { return 1.0f / (1.0f + __expf(-x)); }
__device__ __forceinline__ float tanhf_(float x) {
  float ax = fabsf(x);
  float e = __expf(-2.0f * ax);
  float t = (1.0f - e) / (1.0f + e);
  return copysignf(t, x);
}

// ---------------- P1: x -> xTb[t][kb][b][ko] bf16, LDS-tiled transpose ----
__global__ void k_xT(const float* __restrict__ x, unsigned short* __restrict__ xTb) {
  __shared__ float tile[16][776];
  const int t = blockIdx.x;
  const int tid = threadIdx.x;
  for (int chunk = 0; chunk < 8; ++chunk) {
    #pragma unroll
    for (int i = 0; i < 12; ++i) {
      int id = i * 256 + tid;
      int bl = id / 192, d4 = id % 192;
      int b = chunk * 16 + bl;
      float4 v = *(const float4*)(x + ((size_t)b * T_ + t) * D_ + d4 * 4);
      *(float4*)&tile[bl][d4 * 4] = v;
    }
    __syncthreads();
    #pragma unroll
    for (int i = 0; i < 6; ++i) {
      int id = i * 256 + tid;
      int kb = id >> 4, bl = id & 15;
      int b = chunk * 16 + bl;
      const float* src = &tile[bl][kb * 8];
      unsigned short tmp[8];
      #pragma unroll
      for (int k = 0; k < 8; ++k) tmp[k] = f2bf(src[k]);
      *(short8v*)(xTb + (((size_t)t * 96 + kb) * 128 + b) * 8) = *(short8v*)tmp;
    }
    __syncthreads();
  }
}

// ---------------- P2: weight slices, swizzled ----------------------------
__global__ void k_prep_w(const float* __restrict__ wih, const float* __restrict__ whh,
                         unsigned short* __restrict__ Wc) {
  int id  = blockIdx.x * 256 + threadIdx.x;            // exactly 589824
  int wj  = id / 6144;
  int rem = id - wj * 6144;
  int src = rem / 3072; rem -= src * 3072;
  int r   = rem / 96;
  int kcp = rem - r * 96;
  int kc  = kcp ^ (r & 15);
  int grow = (r >> 3) * H_ + wj * 8 + (r & 7);
  const float* W = (src == 0) ? whh : wih;
  const float* p = W + (size_t)grow * D_ + kc * 8;
  float4 v0 = *(const float4*)p;
  float4 v1 = *(const float4*)(p + 4);
  ushort4 o0 = {f2bf(v0.x), f2bf(v0.y), f2bf(v0.z), f2bf(v0.w)};
  ushort4 o1 = {f2bf(v1.x), f2bf(v1.y), f2bf(v1.z), f2bf(v1.w)};
  *(ushort4*)(Wc + (size_t)id * 8)     = o0;
  *(ushort4*)(Wc + (size_t)id * 8 + 4) = o1;
}

// ---------------- P3: bias, h0 -> all replica slot0, zero final ----------
__global__ void k_prep_s(const float* __restrict__ h0,
                         const float* __restrict__ bih, const float* __restrict__ bhh,
                         unsigned short* __restrict__ hrep, float* __restrict__ bias_c,
                         unsigned* __restrict__ finalc) {
  int id = blockIdx.x * 256 + threadIdx.x;             // exactly 98304
  int b = id / 768, j = id - b * 768;
  size_t p = (size_t)(j >> 3) * 1024 + b * 8 + (j & 7);
  unsigned short v = f2bf(h0[id]);
  #pragma unroll
  for (int r = 0; r < NREP; ++r) hrep[(size_t)r * 2 * HSLOT_SH + p] = v;
  if (id < 3072) {
    int wj = id >> 5, r = id & 31;
    int grow = (r >> 3) * H_ + wj * 8 + (r & 7);
    bias_c[id] = bih[grow] + bhh[grow];
  }
  for (size_t i = id; i < FINAL_U32; i += 98304) finalc[i] = 0;
}

// ---------------- main recurrent kernel ----------------------------------
__launch_bounds__(256, 1)
__global__ void k_lstm(const unsigned short* __restrict__ xTb,
                       const unsigned short* __restrict__ Wc,
                       const float* __restrict__ bias_c,
                       const float* __restrict__ c0,
                       unsigned short* __restrict__ hrep, // [4][2][98304] bf16
                       unsigned* finalc,                  // [1025][16]
                       float* __restrict__ out,
                       float* __restrict__ hT,
                       float* __restrict__ cT) {
  __shared__ __align__(16) unsigned short Wl[2 * 32 * 768];   // 96 KB
  __shared__ float bias_l[32];

  const int wj   = blockIdx.x;
  const int tid  = threadIdx.x;
  const int wave = tid >> 6;          // band: batch rows wave*32..+32
  const int lane = tid & 63;
  const int col  = lane & 31;
  const int kh   = lane >> 5;
  const int sw   = col & 15;

  {
    const short8v* s = (const short8v*)(Wc + (size_t)wj * 49152);
    short8v* d = (short8v*)Wl;
    for (int i = tid; i < 6144; i += 256) d[i] = s[i];
    if (tid < 32) bias_l[tid] = bias_c[wj * 32 + tid];
  }
  __syncthreads();

  const int bg = wave * 32 + col;     // global batch row
  const int jg = wj * 8 + 4 * kh;

  float c_r[4];
  {
    float4 v = *(const float4*)(c0 + (size_t)bg * H_ + jg);
    c_r[0] = v.x; c_r[1] = v.y; c_r[2] = v.z; c_r[3] = v.w;
  }

  const char* wlb = (const char*)Wl;
  const int wrow0 = col * 1536;             // W_hh A-row base (bytes)
  const int wrow1 = 49152 + col * 1536;     // W_ih A-row base

  const unsigned short* rd_rep = hrep + (size_t)(wj & (NREP - 1)) * 2 * HSLOT_SH;

  float bias_r[16];
  #pragma unroll
  for (int q = 0; q < 16; ++q) bias_r[q] = bias_l[(q & 3) + 8 * (q >> 2) + 4 * kh];

  f32x16 accs[4];
  { // phase X for t=0
    #pragma unroll
    for (int q = 0; q < 16; ++q) {
      accs[0][q] = bias_r[q]; accs[1][q] = 0.f; accs[2][q] = 0.f; accs[3][q] = 0.f;
    }
    const unsigned short* xp = xTb + (size_t)kh * 1024 + bg * 8;
    #pragma unroll
    for (int f = 0; f < 48; ++f) {
      short8v w = *(const short8v*)(wlb + wrow1 + (((2 * f + kh) ^ sw) << 4));
      short8v xv = *(const short8v*)(xp + f * 2048);
      accs[f & 3] = __builtin_amdgcn_mfma_f32_32x32x16_bf16(w, xv, accs[f & 3], 0, 0, 0);
    }
  }

  for (int t = 0; t < T_; ++t) {
    if (t > 0) {
      if (wave == 0) {
        const unsigned* fp = finalc + (size_t)t * 16;
        for (;;) {
          unsigned v = __hip_atomic_load(fp, __ATOMIC_RELAXED, __HIP_MEMORY_SCOPE_AGENT);
          if (v >= (unsigned)NWG) break;
          __builtin_amdgcn_s_sleep(4);
        }
      }
      __syncthreads();
      asm volatile("" ::: "memory");
    }

    // phase H: 48 coalesced sc1 16B loads from MY replica, split-drain MFMA
    short8v hfrag[48];
    {
      const unsigned short* hp =
          rd_rep + (size_t)(t & 1) * HSLOT_SH + (size_t)kh * 1024 + bg * 8;
      #pragma unroll
      for (int f = 0; f < 48; ++f) {
        asm volatile("global_load_dwordx4 %0, %1, off sc0 sc1"
                     : "=v"(hfrag[f]) : "v"(hp + f * 2048));
      }
    }
    asm volatile("s_waitcnt vmcnt(24)" ::: "memory");
    __builtin_amdgcn_sched_barrier(0);
    #pragma unroll
    for (int f = 0; f < 24; ++f) {
      short8v w = *(const short8v*)(wlb + wrow0 + (((2 * f + kh) ^ sw) << 4));
      accs[f & 3] = __builtin_amdgcn_mfma_f32_32x32x16_bf16(w, hfrag[f], accs[f & 3], 0, 0, 0);
    }
    asm volatile("s_waitcnt vmcnt(0)" ::: "memory");
    __builtin_amdgcn_sched_barrier(0);
    #pragma unroll
    for (int f = 24; f < 48; ++f) {
      short8v w = *(const short8v*)(wlb + wrow0 + (((2 * f + kh) ^ sw) << 4));
      accs[f & 3] = __builtin_amdgcn_mfma_f32_32x32x16_bf16(w, hfrag[f], accs[f & 3], 0, 0, 0);
    }

    f32x16 g;
    #pragma unroll
    for (int q = 0; q < 16; ++q)
      g[q] = (accs[0][q] + accs[1][q]) + (accs[2][q] + accs[3][q]);

    float hnew[4];
    #pragma unroll
    for (int m = 0; m < 4; ++m) {
      float gi = g[m];
      float gf = g[4 + m];
      float gg = g[8 + m];
      float go = g[12 + m];
      float cn = sigmf(gf) * c_r[m] + sigmf(gi) * tanhf_(gg);
      c_r[m] = cn;
      hnew[m] = sigmf(go) * tanhf_(cn);
    }

    // h exchange: write all 4 replicas (coalesced 8B sc1 write-through)
    union { ushort4 s; unsigned long long u; } hv;
    hv.s = (ushort4){f2bf(hnew[0]), f2bf(hnew[1]), f2bf(hnew[2]), f2bf(hnew[3])};
    {
      size_t off = (size_t)((t + 1) & 1) * HSLOT_SH + (size_t)wj * 1024 + bg * 8 + 4 * kh;
      #pragma unroll
      for (int r = 0; r < NREP; ++r) {
        __hip_atomic_store(
            (unsigned long long*)(hrep + (size_t)r * 2 * HSLOT_SH + off),
            hv.u, __ATOMIC_RELAXED, __HIP_MEMORY_SCOPE_AGENT);
      }
    }

    // release: per-wave store ack, barrier (all waves acked), ONE arrival add
    asm volatile("s_waitcnt vmcnt(0)" ::: "memory");
    __syncthreads();
    if (tid == 0)
      __hip_atomic_fetch_add(finalc + (size_t)(t + 1) * 16, 1u,
                             __ATOMIC_RELAXED, __HIP_MEMORY_SCOPE_AGENT);

    // out stores AFTER the release (off the critical path)
    float4 ov = make_float4(hnew[0], hnew[1], hnew[2], hnew[3]);
    *(float4*)(out + ((size_t)bg * T_ + t) * H_ + jg) = ov;
    if (t == T_ - 1) {
      *(float4*)(hT + (size_t)bg * H_ + jg) = ov;
      float4 cv = make_float4(c_r[0], c_r[1], c_r[2], c_r[3]);
      *(float4*)(cT + (size_t)bg * H_ + jg) = cv;
    }

    // phase X for t+1 (cached coalesced loads), in the shadow of the wait
    if (t + 1 < T_) {
      #pragma unroll
      for (int q = 0; q < 16; ++q) {
        accs[0][q] = bias_r[q]; accs[1][q] = 0.f; accs[2][q] = 0.f; accs[3][q] = 0.f;
      }
      const unsigned short* xp =
          xTb + (size_t)(t + 1) * 98304 + (size_t)kh * 1024 + bg * 8;
      #pragma unroll
      for (int f = 0; f < 48; ++f) {
        short8v w = *(const short8v*)(wlb + wrow1 + (((2 * f + kh) ^ sw) << 4));
        short8v xv = *(const short8v*)(xp + f * 2048);
        accs[f & 3] = __builtin_amdgcn_mfma_f32_32x32x16_bf16(w, xv, accs[f & 3], 0, 0, 0);
      }
    }
  }
}

extern "C" void kernel_launch(void* const* d_in, const int* in_sizes, int n_in,
                              void* d_out, int out_size, void* d_ws, size_t ws_size,
                              hipStream_t stream) {
  const float* x   = (const float*)d_in[0];
  const float* h0  = (const float*)d_in[1];
  const float* c0  = (const float*)d_in[2];
  const float* wih = (const float*)d_in[3];
  const float* whh = (const float*)d_in[4];
  const float* bih = (const float*)d_in[5];
  const float* bhh = (const float*)d_in[6];

  float* out = (float*)d_out;
  float* hT  = out + (size_t)B_ * T_ * H_;
  float* cT  = hT + (size_t)B_ * H_;

  if (ws_size < WS_NEED) return;  // visible failure instead of OOB corruption

  char* ws = (char*)d_ws;
  unsigned*       finalc = (unsigned*)(ws);
  unsigned short* hrep   = (unsigned short*)(ws + HREP_OFF);
  float*          biasc  = (float*)(ws + BIAS_OFF);
  unsigned short* Wc     = (unsigned short*)(ws + WC_OFF);
  unsigned short* xTp    = (unsigned short*)(ws + XT_OFF);

  k_xT<<<dim3(T_), dim3(256), 0, stream>>>(x, xTp);
  k_prep_w<<<dim3(589824 / 256), dim3(256), 0, stream>>>(wih, whh, Wc);
  k_prep_s<<<dim3((B_ * H_) / 256), dim3(256), 0, stream>>>(h0, bih, bhh, hrep, biasc, finalc);
  k_lstm<<<dim3(NWG), dim3(256), 0, stream>>>(xTp, Wc, biasc, c0, hrep, finalc, out, hT, cT);
}